// Round 6
// baseline (1079.699 us; speedup 1.0000x reference)
//
#include <hip/hip_runtime.h>
#include <hip/hip_bf16.h>

// Shapes: B=128, C=16, H=9, T=2048, L=9, TAU=1.0
// Output: (B,2,C,H,L) float32

#define CB 16
#define HH 9
#define TT0 2048
#define RS_SLOT 36864   // 256*16*9 floats per tile slot
#define LPITCH 20       // LDS row pitch in floats (80B: 16B-aligned, spreads banks)

__device__ __forceinline__ float ftanh(float x) {
    float e = __expf(2.f * x);
    return 1.f - 2.f / (e + 1.f);
}
__device__ __forceinline__ float fprelu(float v, float a) {
    return v >= 0.f ? v : a * v;
}
__device__ __forceinline__ void ld16(const float* p, float* v) {
#pragma unroll
    for (int q = 0; q < 4; ++q) {
        float4 f = *(const float4*)(p + 4 * q);
        v[4 * q] = f.x; v[4 * q + 1] = f.y; v[4 * q + 2] = f.z; v[4 * q + 3] = f.w;
    }
}
__device__ __forceinline__ void ld16s(const float* p, float* v) {  // LDS variant
#pragma unroll
    for (int q = 0; q < 4; ++q) {
        float4 f = *(const float4*)(p + 4 * q);
        v[4 * q] = f.x; v[4 * q + 1] = f.y; v[4 * q + 2] = f.z; v[4 * q + 3] = f.w;
    }
}
__device__ __forceinline__ void st16(float* p, const float* v) {
#pragma unroll
    for (int q = 0; q < 4; ++q) {
        float4 f; f.x = v[4 * q]; f.y = v[4 * q + 1]; f.z = v[4 * q + 2]; f.w = v[4 * q + 3];
        *(float4*)(p + 4 * q) = f;
    }
}
__device__ __forceinline__ int refl(int u, int t) {
    return u < 0 ? -u : (u >= t ? 2 * t - 2 - u : u);
}

// Block reduction of 16 per-thread values -> rs slot. Leading AND internal
// syncthreads: safe to call twice; leading sync orders prior LDS writes.
__device__ __forceinline__ void rowsum_reduce(const float* vals, float* rs, int tile,
                                              int b, int h, int sdx, int tid) {
    __shared__ float red[4 * CB];
    const int lane = tid & 63, wv = tid >> 6;
    __syncthreads();
#pragma unroll
    for (int cc = 0; cc < CB; ++cc) {
        float s = vals[cc];
#pragma unroll
        for (int off = 32; off >= 1; off >>= 1) s += __shfl_xor(s, off, 64);
        if (lane == cc) red[wv * CB + cc] = s;
    }
    __syncthreads();
    if (tid < CB) {
        float s = red[tid] + red[CB + tid] + red[2 * CB + tid] + red[3 * CB + tid];
        rs[(size_t)tile * RS_SLOT + ((size_t)(2 * b + sdx) * CB + tid) * HH + h] = s;
    }
}

// ---------------- Weight transpose (FMA-inner index contiguous) ----------------
// W: [0,528) Wc1t[k][cc]; [528,1296) Wc2t[k][c2][cc];
// [1296+i*2048): WU1t[k][c2][cc](768), WU2t[c2][cc](256), WP1t(768), WP2t(256)
__global__ void wtrans_kernel(const float* __restrict__ Wc1, const float* __restrict__ Wc2,
                              const float* __restrict__ WU1, const float* __restrict__ WU2,
                              const float* __restrict__ WP1, const float* __restrict__ WP2,
                              float* __restrict__ W)
{
    const int tid = threadIdx.x;
    for (int idx = tid; idx < 528; idx += 256) {
        int k = idx >> 4, cc = idx & 15;
        W[idx] = Wc1[cc * 33 + k];
    }
    for (int idx = tid; idx < 768; idx += 256) {
        int k = idx >> 8, c2 = (idx >> 4) & 15, cc = idx & 15;
        W[528 + idx] = Wc2[(cc * 16 + c2) * 3 + k];
    }
    for (int i = 0; i < 9; ++i) {
        float* base = W + 1296 + i * 2048;
        const float* wu1 = WU1 + i * 768;
        const float* wp1 = WP1 + i * 768;
        const float* wu2 = WU2 + i * 256;
        const float* wp2 = WP2 + i * 256;
        for (int idx = tid; idx < 768; idx += 256) {
            int k = idx >> 8, c2 = (idx >> 4) & 15, cc = idx & 15;
            base[idx]        = wu1[cc * 48 + c2 * 3 + k];
            base[1024 + idx] = wp1[cc * 48 + c2 * 3 + k];
        }
        {
            int idx = tid;
            if (idx < 256) {
                int c2 = idx >> 4, cc = idx & 15;
                base[768 + idx]  = wu2[cc * 16 + c2];
                base[1792 + idx] = wp2[cc * 16 + c2];
            }
        }
    }
}

// c[j] = sm*even[j] + tanh(sm * (W2 . prelu(conv3(odd)))); keeps raw odd[j] in ow1.
__device__ __forceinline__ void compute_c(
    const float* __restrict__ xrow, int j, int t, float sm,
    const float* __restrict__ W1, const float* __restrict__ W2, float aU,
    float* cv, float* ow1)
{
    float accz[CB];
#pragma unroll
    for (int i = 0; i < CB; ++i) accz[i] = 0.f;
#pragma unroll
    for (int k = 0; k < 3; ++k) {
        int um = refl(j - 1 + k, t);
        float ow[CB];
        ld16(xrow + (size_t)(2 * um + 1) * CB, ow);
        if (k == 1) {
#pragma unroll
            for (int i = 0; i < CB; ++i) ow1[i] = ow[i];
        }
#pragma unroll
        for (int c2 = 0; c2 < CB; ++c2) {
            float o = ow[c2];
            const float* wp = W1 + (k * 16 + c2) * 16;
#pragma unroll
            for (int cc = 0; cc < CB; ++cc)
                accz[cc] = fmaf(wp[cc], o, accz[cc]);
        }
    }
#pragma unroll
    for (int i = 0; i < CB; ++i) accz[i] = fprelu(accz[i], aU);
    float bacc[CB];
#pragma unroll
    for (int cc = 0; cc < CB; ++cc) bacc[cc] = 0.f;
#pragma unroll
    for (int c2 = 0; c2 < CB; ++c2) {
        float z = accz[c2];
        const float* wp = W2 + c2 * 16;
#pragma unroll
        for (int cc = 0; cc < CB; ++cc)
            bacc[cc] = fmaf(wp[cc], z, bacc[cc]);
    }
    float ev[CB];
    ld16(xrow + (size_t)(2 * j) * CB, ev);
#pragma unroll
    for (int cc = 0; cc < CB; ++cc)
        cv[cc] = sm * ev[cc] + ftanh(sm * bacc[cc]);
}

// ---------------- Front: conv33+BN+PReLU -> conv3(16x16)+BN+PReLU ----------------
__global__ __launch_bounds__(256, 4) void front_kernel(
    const float* __restrict__ x, const float* __restrict__ Wt,
    const float* __restrict__ bc1,
    const float* __restrict__ bn1g, const float* __restrict__ bn1b,
    const float* __restrict__ ac1,
    const float* __restrict__ bc2,
    const float* __restrict__ bn2g, const float* __restrict__ bn2b,
    const float* __restrict__ ac2,
    float* __restrict__ y)
{
    const int tid = threadIdx.x;
    const int t0  = blockIdx.x * 254;
    const int h   = blockIdx.y;
    const int b   = blockIdx.z;
    const float* Wc1t = Wt;
    const float* Wc2t = Wt + 528;

    __shared__ float lds_x[288];
    __shared__ float lds_y[256 * LPITCH];

    const float* xrow = x + (size_t)(b * HH + h) * TT0;
    {
        int g = t0 - 17 + tid;
        lds_x[tid] = (g >= 0 && g < TT0) ? xrow[g] : 0.f;
        if (tid < 32) {
            int g2 = t0 + 239 + tid;
            lds_x[256 + tid] = (g2 >= 0 && g2 < TT0) ? xrow[g2] : 0.f;
        }
    }
    __syncthreads();

    const float a1 = ac1[0], a2 = ac2[0];
    float acc[CB];
#pragma unroll
    for (int cc = 0; cc < CB; ++cc) acc[cc] = bc1[cc];
#pragma unroll
    for (int k = 0; k < 33; ++k) {
        float xv = lds_x[tid + k];
        const float* wp = Wc1t + k * 16;
#pragma unroll
        for (int cc = 0; cc < CB; ++cc) acc[cc] = fmaf(wp[cc], xv, acc[cc]);
    }
#pragma unroll
    for (int cc = 0; cc < CB; ++cc)
        lds_y[tid * LPITCH + cc] = fprelu(acc[cc] * bn1g[cc] + bn1b[cc], a1);
    __syncthreads();

    const int jt = t0 + tid;
    if (tid < 254 && jt < TT0) {
        float acc2[CB];
#pragma unroll
        for (int cc = 0; cc < CB; ++cc) acc2[cc] = bc2[cc];
#pragma unroll
        for (int k = 0; k < 3; ++k) {
            int u = jt - 1 + k;
            if (u >= 0 && u < TT0) {
                float yv[CB];
                ld16s(&lds_y[(tid + k) * LPITCH], yv);
#pragma unroll
                for (int c2 = 0; c2 < CB; ++c2) {
                    float yvv = yv[c2];
                    const float* wp = Wc2t + (k * 16 + c2) * 16;
#pragma unroll
                    for (int cc = 0; cc < CB; ++cc)
                        acc2[cc] = fmaf(wp[cc], yvv, acc2[cc]);
                }
            }
        }
        float ov[CB];
#pragma unroll
        for (int cc = 0; cc < CB; ++cc) ov[cc] = fprelu(acc2[cc] * bn2g[cc] + bn2b[cc], a2);
        st16(y + ((size_t)(b * HH + h) * TT0 + jt) * CB, ov);
    }
}

// ---------------- Fused c+d level (levels 0..4) ----------------
// c-phase -> global xout + LDS tile (+halo by lanes 0/1); d-phase entirely from
// LDS c-tile + registers (odd[j] kept from the k=1 tap). No global reads in d.
__global__ __launch_bounds__(256, 2) void cd_kernel(
    const float* __restrict__ xin, float* __restrict__ xout,
    float* __restrict__ rs, const float* __restrict__ m0prev,
    const float* __restrict__ Wt,   // WU1t 0..768, WU2t 768..1024, WP1t 1024..1792, WP2t 1792..2048
    const float* __restrict__ aUp, const float* __restrict__ aPp, const int t)
{
    const int tid  = threadIdx.x;
    const int row  = blockIdx.x;          // b*9 + h
    const int tile = blockIdx.y;          // 256 positions per tile
    const int b = row / 9, h = row - 9 * b;
    const float sm = m0prev ? m0prev[b] : 1.f;
    const float aU = aUp[0], aP = aPp[0];
    const float* xrow = xin + (size_t)row * (2 * t) * CB;
    const int p0 = tile * 256;
    const int j = p0 + tid;
    const bool valid = (j < t);

    const float* WU1t = Wt;
    const float* WU2t = Wt + 768;
    const float* WP1t = Wt + 1024;
    const float* WP2t = Wt + 1792;

    __shared__ float ldc[258 * LPITCH];   // c[p0-1 .. p0+256], idx = j-p0+1

    float cv[CB], ow1[CB];
#pragma unroll
    for (int i = 0; i < CB; ++i) { cv[i] = 0.f; ow1[i] = 0.f; }

    if (valid) {
        compute_c(xrow, j, t, sm, WU1t, WU2t, aU, cv, ow1);
        st16(&ldc[(tid + 1) * LPITCH], cv);
        st16(xout + ((size_t)row * t + j) * CB, cv);
    }
    if (tid < 2) {                         // halo (LDS only)
        int jx = (tid == 0) ? p0 - 1 : p0 + 256;
        if (jx >= 0 && jx < t) {
            float hv[CB], dump[CB];
            compute_c(xrow, jx, t, sm, WU1t, WU2t, aU, hv, dump);
            st16(&ldc[(jx - p0 + 1) * LPITCH], hv);
        }
    }

    rowsum_reduce(cv, rs, tile, b, h, 0, tid);   // leading sync -> ldc visible

    // ---- d-phase ----
    float dv[CB];
#pragma unroll
    for (int i = 0; i < CB; ++i) dv[i] = 0.f;

    if (valid) {
        float accz[CB];
#pragma unroll
        for (int i = 0; i < CB; ++i) accz[i] = 0.f;
#pragma unroll
        for (int k = 0; k < 3; ++k) {
            int um = refl(j - 1 + k, t);
            int li = um - p0 + 1;
            float cw[CB];
            ld16s(&ldc[li * LPITCH], cw);
#pragma unroll
            for (int c2 = 0; c2 < CB; ++c2) {
                float o = cw[c2];
                const float* wp = WP1t + (k * 16 + c2) * 16;
#pragma unroll
                for (int cc = 0; cc < CB; ++cc)
                    accz[cc] = fmaf(wp[cc], o, accz[cc]);
            }
        }
#pragma unroll
        for (int i = 0; i < CB; ++i) accz[i] = fprelu(accz[i], aP);
        float bacc[CB];
#pragma unroll
        for (int cc = 0; cc < CB; ++cc) bacc[cc] = 0.f;
#pragma unroll
        for (int c2 = 0; c2 < CB; ++c2) {
            float z = accz[c2];
            const float* wp = WP2t + c2 * 16;
#pragma unroll
            for (int cc = 0; cc < CB; ++cc)
                bacc[cc] = fmaf(wp[cc], z, bacc[cc]);
        }
#pragma unroll
        for (int cc = 0; cc < CB; ++cc)
            dv[cc] = sm * ow1[cc] - ftanh(bacc[cc]);
    }
    rowsum_reduce(dv, rs, tile, b, h, 1, tid);
}

// ---------------- Gate (levels 0..4): one block per bj = b*2+s ----------------
__global__ __launch_bounds__(192) void gate_kernel(
    const float* __restrict__ rs, const float* __restrict__ gn,
    const float* __restrict__ Wg1, const float* __restrict__ ag1p,
    const float* __restrict__ Wg2, const float* __restrict__ ag2p,
    float* __restrict__ out, float* __restrict__ m0buf,
    const int t, const int nt, const int li)
{
    const int bj  = blockIdx.x;
    const int tid = threadIdx.x;

    __shared__ float sums[144];
    __shared__ float sscale;

    if (tid < 144) {
        float s = 0.f;
        for (int tl = 0; tl < nt; ++tl)
            s += rs[(size_t)tl * RS_SLOT + (size_t)bj * 144 + tid];
        sums[tid] = s;
    }
    __syncthreads();

    if (tid == 0) {
        const float ag1 = ag1p[0], ag2 = ag2p[0];
        const float inv = 1.f / (9.f * (float)t);
        float pooled[CB];
#pragma unroll
        for (int cc = 0; cc < CB; ++cc) {
            float s = 0.f;
#pragma unroll
            for (int h = 0; h < HH; ++h) s += sums[cc * HH + h];
            pooled[cc] = s * inv;
        }
        float hm1[CB];
#pragma unroll
        for (int cc = 0; cc < CB; ++cc) {
            float s = 0.f;
#pragma unroll
            for (int c2 = 0; c2 < CB; ++c2) s = fmaf(Wg1[cc * CB + c2], pooled[c2], s);
            hm1[cc] = fprelu(s, ag1);
        }
        float h0 = 0.f, h1 = 0.f;
#pragma unroll
        for (int c2 = 0; c2 < CB; ++c2) {
            h0 = fmaf(Wg2[c2], hm1[c2], h0);
            h1 = fmaf(Wg2[CB + c2], hm1[c2], h1);
        }
        h0 = fprelu(h0, ag2); h1 = fprelu(h1, ag2);
        float mx = fmaxf(h0, h1);
        float e0 = __expf(h0 - mx), e1 = __expf(h1 - mx);
        float s0 = e0 / (e0 + e1), s1 = e1 / (e0 + e1);
        float a0 = s0 + gn[bj * 2 + 0], a1 = s1 + gn[bj * 2 + 1];
        float mx2 = fmaxf(a0, a1);
        float f0 = __expf(a0 - mx2), f1 = __expf(a1 - mx2);
        float m0 = f0 / (f0 + f1), m1 = f1 / (f0 + f1);
        sscale = m1 / (float)t;
        if ((bj & 1) == 0) m0buf[bj >> 1] = m0;
    }
    __syncthreads();

    if (tid < 144)
        out[(size_t)(bj * 144 + tid) * 9 + li] = sums[tid] * sscale;
}

// ---------------- Tail: levels 5..8 + gates, one block per batch b ----------------
__global__ __launch_bounds__(256) void tail_kernel(
    const float* __restrict__ xin,      // level-5 input: rows b*9+h, 64 pos, 16 ch
    const float* __restrict__ m0in,     // m0 from gate 4
    const float* __restrict__ Wt,       // transposed weight base
    const float* __restrict__ aUa, const float* __restrict__ aPa,
    const float* __restrict__ gn,       // full (L,2B,2)
    const float* __restrict__ Wg1a, const float* __restrict__ ag1a,
    const float* __restrict__ Wg2a, const float* __restrict__ ag2a,
    float* __restrict__ out)
{
    const int b   = blockIdx.x;
    const int tid = threadIdx.x;

    __shared__ float bufA[9216];   // 9*64*16
    __shared__ float bufB[4608];   // 9*32*16
    __shared__ float sums[288];    // [s][cc*9+h]
    __shared__ float sh_sm, sh_sc0, sh_sc1;

    for (int idx = tid; idx < 9216; idx += 256)
        bufA[idx] = xin[(size_t)b * 9216 + idx];
    if (tid == 0) sh_sm = m0in[b];
    __syncthreads();

    float* cur = bufA;
    float* cb  = bufB;
    int t = 32;
    for (int l = 5; l <= 8; ++l) {
        const float* W    = Wt + 1296 + l * 2048;
        const float* WU1t = W;
        const float* WU2t = W + 768;
        const float* WP1t = W + 1024;
        const float* WP2t = W + 1792;
        const float aU = aUa[l], aP = aPa[l];
        const float sm = sh_sm;
        const int t2 = 2 * t;

        for (int idx = tid; idx < 288; idx += 256) sums[idx] = 0.f;
        __syncthreads();

        // ---- c-phase ----
        for (int item = tid; item < 9 * t; item += 256) {
            int h = item / t, j = item - h * t;
            const float* xr = cur + h * t2 * CB;
            float accz[CB];
#pragma unroll
            for (int i = 0; i < CB; ++i) accz[i] = 0.f;
#pragma unroll
            for (int k = 0; k < 3; ++k) {
                int um = refl(j - 1 + k, t);
                float ow[CB];
                ld16s(xr + (2 * um + 1) * CB, ow);
#pragma unroll
                for (int c2 = 0; c2 < CB; ++c2) {
                    float o = ow[c2];
                    const float* wp = WU1t + (k * 16 + c2) * 16;
#pragma unroll
                    for (int cc = 0; cc < CB; ++cc)
                        accz[cc] = fmaf(wp[cc], o, accz[cc]);
                }
            }
#pragma unroll
            for (int i = 0; i < CB; ++i) accz[i] = fprelu(accz[i], aU);
            float bacc[CB];
#pragma unroll
            for (int cc = 0; cc < CB; ++cc) bacc[cc] = 0.f;
#pragma unroll
            for (int c2 = 0; c2 < CB; ++c2) {
                float z = accz[c2];
                const float* wp = WU2t + c2 * 16;
#pragma unroll
                for (int cc = 0; cc < CB; ++cc)
                    bacc[cc] = fmaf(wp[cc], z, bacc[cc]);
            }
            float ev[CB];
            ld16s(xr + (2 * j) * CB, ev);
            float cvv[CB];
#pragma unroll
            for (int cc = 0; cc < CB; ++cc) {
                cvv[cc] = sm * ev[cc] + ftanh(sm * bacc[cc]);
                atomicAdd(&sums[cc * HH + h], cvv[cc]);
            }
            st16(cb + (h * t + j) * CB, cvv);
        }
        __syncthreads();

        // ---- d-phase ----
        for (int item = tid; item < 9 * t; item += 256) {
            int h = item / t, j = item - h * t;
            const float* xr = cur + h * t2 * CB;
            const float* cr = cb + h * t * CB;
            float accz[CB];
#pragma unroll
            for (int i = 0; i < CB; ++i) accz[i] = 0.f;
#pragma unroll
            for (int k = 0; k < 3; ++k) {
                int um = refl(j - 1 + k, t);
                float cw[CB];
                ld16s(cr + um * CB, cw);
#pragma unroll
                for (int c2 = 0; c2 < CB; ++c2) {
                    float o = cw[c2];
                    const float* wp = WP1t + (k * 16 + c2) * 16;
#pragma unroll
                    for (int cc = 0; cc < CB; ++cc)
                        accz[cc] = fmaf(wp[cc], o, accz[cc]);
                }
            }
#pragma unroll
            for (int i = 0; i < CB; ++i) accz[i] = fprelu(accz[i], aP);
            float bacc[CB];
#pragma unroll
            for (int cc = 0; cc < CB; ++cc) bacc[cc] = 0.f;
#pragma unroll
            for (int c2 = 0; c2 < CB; ++c2) {
                float z = accz[c2];
                const float* wp = WP2t + c2 * 16;
#pragma unroll
                for (int cc = 0; cc < CB; ++cc)
                    bacc[cc] = fmaf(wp[cc], z, bacc[cc]);
            }
            float ov[CB];
            ld16s(xr + (2 * j + 1) * CB, ov);
#pragma unroll
            for (int cc = 0; cc < CB; ++cc)
                atomicAdd(&sums[144 + cc * HH + h], sm * ov[cc] - ftanh(bacc[cc]));
        }
        __syncthreads();

        // ---- gate (threads 0 and 1 handle s=0 / s=1) ----
        if (tid < 2) {
            const int s = tid;
            const float ag1 = ag1a[l], ag2 = ag2a[l];
            const float* Wg1 = Wg1a + l * 256;
            const float* Wg2 = Wg2a + l * 32;
            const float inv = 1.f / (9.f * (float)t);
            float pooled[CB];
#pragma unroll
            for (int cc = 0; cc < CB; ++cc) {
                float ss = 0.f;
#pragma unroll
                for (int h = 0; h < HH; ++h) ss += sums[s * 144 + cc * HH + h];
                pooled[cc] = ss * inv;
            }
            float hm1[CB];
#pragma unroll
            for (int cc = 0; cc < CB; ++cc) {
                float ss = 0.f;
#pragma unroll
                for (int c2 = 0; c2 < CB; ++c2) ss = fmaf(Wg1[cc * CB + c2], pooled[c2], ss);
                hm1[cc] = fprelu(ss, ag1);
            }
            float h0 = 0.f, h1 = 0.f;
#pragma unroll
            for (int c2 = 0; c2 < CB; ++c2) {
                h0 = fmaf(Wg2[c2], hm1[c2], h0);
                h1 = fmaf(Wg2[CB + c2], hm1[c2], h1);
            }
            h0 = fprelu(h0, ag2); h1 = fprelu(h1, ag2);
            float mx = fmaxf(h0, h1);
            float e0 = __expf(h0 - mx), e1 = __expf(h1 - mx);
            float s0 = e0 / (e0 + e1), s1 = e1 / (e0 + e1);
            const int bj = b * 2 + s;
            float a0 = s0 + gn[(size_t)l * 512 + bj * 2 + 0];
            float a1 = s1 + gn[(size_t)l * 512 + bj * 2 + 1];
            float mx2 = fmaxf(a0, a1);
            float f0 = __expf(a0 - mx2), f1 = __expf(a1 - mx2);
            float m0 = f0 / (f0 + f1), m1 = f1 / (f0 + f1);
            if (s == 0) { sh_sc0 = m1 / (float)t; sh_sm = m0; }
            else        { sh_sc1 = m1 / (float)t; }
        }
        __syncthreads();

        for (int idx = tid; idx < 288; idx += 256) {
            int s = idx / 144, rem = idx - s * 144;
            float sc = s ? sh_sc1 : sh_sc0;
            out[(size_t)(((b * 2 + s) * 144) + rem) * 9 + l] = sums[idx] * sc;
        }
        __syncthreads();

        float* tmp = cur; cur = cb; cb = tmp;
        t >>= 1;
    }
}

extern "C" void kernel_launch(void* const* d_in, const int* in_sizes, int n_in,
                              void* d_out, int out_size, void* d_ws, size_t ws_size,
                              hipStream_t stream) {
    const float* x    = (const float*)d_in[0];
    const float* gn   = (const float*)d_in[1];
    const float* Wc1  = (const float*)d_in[2];
    const float* bc1  = (const float*)d_in[3];
    const float* bn1g = (const float*)d_in[4];
    const float* bn1b = (const float*)d_in[5];
    const float* ac1  = (const float*)d_in[6];
    const float* Wc2  = (const float*)d_in[7];
    const float* bc2  = (const float*)d_in[8];
    const float* bn2g = (const float*)d_in[9];
    const float* bn2b = (const float*)d_in[10];
    const float* ac2  = (const float*)d_in[11];
    const float* WP1  = (const float*)d_in[12];
    const float* aP   = (const float*)d_in[13];
    const float* WP2  = (const float*)d_in[14];
    const float* WU1  = (const float*)d_in[15];
    const float* aU   = (const float*)d_in[16];
    const float* WU2  = (const float*)d_in[17];
    const float* Wg1  = (const float*)d_in[18];
    const float* ag1  = (const float*)d_in[19];
    const float* Wg2  = (const float*)d_in[20];
    const float* ag2  = (const float*)d_in[21];
    float* out = (float*)d_out;

    char* ws = (char*)d_ws;
    const size_t sz0 = (size_t)128 * 9 * 2048 * 16 * 4;   // 150,994,944
    const size_t sz1 = sz0 / 2;
    float* buf0 = (float*)ws;
    float* buf1 = (float*)(ws + sz0);
    float* rs   = (float*)(ws + sz0 + sz1);
    float* m0b  = (float*)(ws + sz0 + sz1 + (size_t)4 * RS_SLOT * 4);
    float* wt   = (float*)(ws + sz0 + sz1 + (size_t)4 * RS_SLOT * 4 + 512);

    wtrans_kernel<<<1, 256, 0, stream>>>(Wc1, Wc2, WU1, WU2, WP1, WP2, wt);

    dim3 fgrid(9, 9, 128);
    front_kernel<<<fgrid, 256, 0, stream>>>(x, wt, bc1, bn1g, bn1b, ac1,
                                            bc2, bn2g, bn2b, ac2, buf0);

    float* cur = buf0;
    float* nxt = buf1;
    int t = 1024;
    for (int i = 0; i < 5; ++i) {
        const int nt = (t + 255) >> 8;
        const float* m0p = (i == 0) ? nullptr : m0b;
        const float* lw = wt + 1296 + i * 2048;
        dim3 lgrid(128 * 9, nt);
        cd_kernel<<<lgrid, 256, 0, stream>>>(cur, nxt, rs, m0p, lw, aU + i, aP + i, t);
        gate_kernel<<<256, 192, 0, stream>>>(
            rs, gn + i * 512, Wg1 + i * 256, ag1 + i, Wg2 + i * 32, ag2 + i,
            out, m0b, t, nt, i);
        float* tmp = cur; cur = nxt; nxt = tmp;
        t >>= 1;
    }
    // cur now holds level-5 input (t=64 rows), produced into buf1.
    tail_kernel<<<128, 256, 0, stream>>>(cur, m0b, wt, aU, aP, gn,
                                         Wg1, ag1, Wg2, ag2, out);
}

// Round 7
// 752.122 us; speedup vs baseline: 1.4355x; 1.4355x over previous
//
#include <hip/hip_runtime.h>
#include <hip/hip_bf16.h>

// Shapes: B=128, C=16, H=9, T=2048, L=9, TAU=1.0
// Output: (B,2,C,H,L) float32

#define CB 16
#define HH 9
#define TT0 2048
#define RS_SLOT 36864   // 256*16*9 floats per tile slot
#define LPITCH 20       // LDS row pitch in floats (80B: 16B-aligned)

__device__ __forceinline__ float ftanh(float x) {
    float e = __expf(2.f * x);
    return 1.f - 2.f / (e + 1.f);
}
__device__ __forceinline__ float fprelu(float v, float a) {
    return v >= 0.f ? v : a * v;
}
__device__ __forceinline__ void ld16(const float* p, float* v) {
#pragma unroll
    for (int q = 0; q < 4; ++q) {
        float4 f = *(const float4*)(p + 4 * q);
        v[4 * q] = f.x; v[4 * q + 1] = f.y; v[4 * q + 2] = f.z; v[4 * q + 3] = f.w;
    }
}
__device__ __forceinline__ void ld16s(const float* p, float* v) {
#pragma unroll
    for (int q = 0; q < 4; ++q) {
        float4 f = *(const float4*)(p + 4 * q);
        v[4 * q] = f.x; v[4 * q + 1] = f.y; v[4 * q + 2] = f.z; v[4 * q + 3] = f.w;
    }
}
__device__ __forceinline__ void st16(float* p, const float* v) {
#pragma unroll
    for (int q = 0; q < 4; ++q) {
        float4 f; f.x = v[4 * q]; f.y = v[4 * q + 1]; f.z = v[4 * q + 2]; f.w = v[4 * q + 3];
        *(float4*)(p + 4 * q) = f;
    }
}
__device__ __forceinline__ int refl(int u, int t) {
    return u < 0 ? -u : (u >= t ? 2 * t - 2 - u : u);
}

// Block reduction of 16 per-thread values -> rs slot. Leading AND internal
// syncthreads: safe to call twice; leading sync orders prior LDS writes.
__device__ __forceinline__ void rowsum_reduce(const float* vals, float* rs, int tile,
                                              int b, int h, int sdx, int tid) {
    __shared__ float red[4 * CB];
    const int lane = tid & 63, wv = tid >> 6;
    __syncthreads();
#pragma unroll
    for (int cc = 0; cc < CB; ++cc) {
        float s = vals[cc];
#pragma unroll
        for (int off = 32; off >= 1; off >>= 1) s += __shfl_xor(s, off, 64);
        if (lane == cc) red[wv * CB + cc] = s;
    }
    __syncthreads();
    if (tid < CB) {
        float s = red[tid] + red[CB + tid] + red[2 * CB + tid] + red[3 * CB + tid];
        rs[(size_t)tile * RS_SLOT + ((size_t)(2 * b + sdx) * CB + tid) * HH + h] = s;
    }
}

// ---------------- Weight transpose (FMA-inner index contiguous) ----------------
// W: [0,528) Wc1t[k][cc]; [528,1296) Wc2t[k][c2][cc];
// [1296+i*2048): WU1t[k][c2][cc](768), WU2t[c2][cc](256), WP1t(768), WP2t(256)
__global__ void wtrans_kernel(const float* __restrict__ Wc1, const float* __restrict__ Wc2,
                              const float* __restrict__ WU1, const float* __restrict__ WU2,
                              const float* __restrict__ WP1, const float* __restrict__ WP2,
                              float* __restrict__ W)
{
    const int tid = threadIdx.x;
    for (int idx = tid; idx < 528; idx += 256) {
        int k = idx >> 4, cc = idx & 15;
        W[idx] = Wc1[cc * 33 + k];
    }
    for (int idx = tid; idx < 768; idx += 256) {
        int k = idx >> 8, c2 = (idx >> 4) & 15, cc = idx & 15;
        W[528 + idx] = Wc2[(cc * 16 + c2) * 3 + k];
    }
    for (int i = 0; i < 9; ++i) {
        float* base = W + 1296 + i * 2048;
        const float* wu1 = WU1 + i * 768;
        const float* wp1 = WP1 + i * 768;
        const float* wu2 = WU2 + i * 256;
        const float* wp2 = WP2 + i * 256;
        for (int idx = tid; idx < 768; idx += 256) {
            int k = idx >> 8, c2 = (idx >> 4) & 15, cc = idx & 15;
            base[idx]        = wu1[cc * 48 + c2 * 3 + k];
            base[1024 + idx] = wp1[cc * 48 + c2 * 3 + k];
        }
        {
            int idx = tid;
            if (idx < 256) {
                int c2 = idx >> 4, cc = idx & 15;
                base[768 + idx]  = wu2[cc * 16 + c2];
                base[1792 + idx] = wp2[cc * 16 + c2];
            }
        }
    }
}

// c[j] = sm*even[j] + tanh(sm * (W2 . prelu(conv3(odd)))); keeps raw odd[j] in ow1.
__device__ __forceinline__ void compute_c(
    const float* __restrict__ xrow, int j, int t, float sm,
    const float* __restrict__ W1, const float* __restrict__ W2, float aU,
    float* cv, float* ow1)
{
    float accz[CB];
#pragma unroll
    for (int i = 0; i < CB; ++i) accz[i] = 0.f;
#pragma unroll
    for (int k = 0; k < 3; ++k) {
        int um = refl(j - 1 + k, t);
        float ow[CB];
        ld16(xrow + (size_t)(2 * um + 1) * CB, ow);
        if (k == 1) {
#pragma unroll
            for (int i = 0; i < CB; ++i) ow1[i] = ow[i];
        }
#pragma unroll
        for (int c2 = 0; c2 < CB; ++c2) {
            float o = ow[c2];
            const float* wp = W1 + (k * 16 + c2) * 16;
#pragma unroll
            for (int cc = 0; cc < CB; ++cc)
                accz[cc] = fmaf(wp[cc], o, accz[cc]);
        }
    }
#pragma unroll
    for (int i = 0; i < CB; ++i) accz[i] = fprelu(accz[i], aU);
    float bacc[CB];
#pragma unroll
    for (int cc = 0; cc < CB; ++cc) bacc[cc] = 0.f;
#pragma unroll
    for (int c2 = 0; c2 < CB; ++c2) {
        float z = accz[c2];
        const float* wp = W2 + c2 * 16;
#pragma unroll
        for (int cc = 0; cc < CB; ++cc)
            bacc[cc] = fmaf(wp[cc], z, bacc[cc]);
    }
    float ev[CB];
    ld16(xrow + (size_t)(2 * j) * CB, ev);
#pragma unroll
    for (int cc = 0; cc < CB; ++cc)
        cv[cc] = sm * ev[cc] + ftanh(sm * bacc[cc]);
}

// ---------------- Front: conv33+BN+PReLU -> conv3(16x16)+BN+PReLU ----------------
__global__ __launch_bounds__(256, 4) void front_kernel(
    const float* __restrict__ x, const float* __restrict__ Wt,
    const float* __restrict__ bc1,
    const float* __restrict__ bn1g, const float* __restrict__ bn1b,
    const float* __restrict__ ac1,
    const float* __restrict__ bc2,
    const float* __restrict__ bn2g, const float* __restrict__ bn2b,
    const float* __restrict__ ac2,
    float* __restrict__ y)
{
    const int tid = threadIdx.x;
    const int t0  = blockIdx.x * 254;
    const int h   = blockIdx.y;
    const int b   = blockIdx.z;
    const float* Wc1t = Wt;
    const float* Wc2t = Wt + 528;

    __shared__ float lds_x[288];
    __shared__ float lds_y[256 * LPITCH];

    const float* xrow = x + (size_t)(b * HH + h) * TT0;
    {
        int g = t0 - 17 + tid;
        lds_x[tid] = (g >= 0 && g < TT0) ? xrow[g] : 0.f;
        if (tid < 32) {
            int g2 = t0 + 239 + tid;
            lds_x[256 + tid] = (g2 >= 0 && g2 < TT0) ? xrow[g2] : 0.f;
        }
    }
    __syncthreads();

    const float a1 = ac1[0], a2 = ac2[0];
    float acc[CB];
#pragma unroll
    for (int cc = 0; cc < CB; ++cc) acc[cc] = bc1[cc];
#pragma unroll
    for (int k = 0; k < 33; ++k) {
        float xv = lds_x[tid + k];
        const float* wp = Wc1t + k * 16;
#pragma unroll
        for (int cc = 0; cc < CB; ++cc) acc[cc] = fmaf(wp[cc], xv, acc[cc]);
    }
#pragma unroll
    for (int cc = 0; cc < CB; ++cc)
        lds_y[tid * LPITCH + cc] = fprelu(acc[cc] * bn1g[cc] + bn1b[cc], a1);
    __syncthreads();

    const int jt = t0 + tid;
    if (tid < 254 && jt < TT0) {
        float acc2[CB];
#pragma unroll
        for (int cc = 0; cc < CB; ++cc) acc2[cc] = bc2[cc];
#pragma unroll
        for (int k = 0; k < 3; ++k) {
            int u = jt - 1 + k;
            if (u >= 0 && u < TT0) {
                float yv[CB];
                ld16s(&lds_y[(tid + k) * LPITCH], yv);
#pragma unroll
                for (int c2 = 0; c2 < CB; ++c2) {
                    float yvv = yv[c2];
                    const float* wp = Wc2t + (k * 16 + c2) * 16;
#pragma unroll
                    for (int cc = 0; cc < CB; ++cc)
                        acc2[cc] = fmaf(wp[cc], yvv, acc2[cc]);
                }
            }
        }
        float ov[CB];
#pragma unroll
        for (int cc = 0; cc < CB; ++cc) ov[cc] = fprelu(acc2[cc] * bn2g[cc] + bn2b[cc], a2);
        st16(y + ((size_t)(b * HH + h) * TT0 + jt) * CB, ov);
    }
}

// ---------------- Fused c+d level (levels 0..4) ----------------
__global__ __launch_bounds__(256, 2) void cd_kernel(
    const float* __restrict__ xin, float* __restrict__ xout,
    float* __restrict__ rs, const float* __restrict__ m0prev,
    const float* __restrict__ Wt,
    const float* __restrict__ aUp, const float* __restrict__ aPp, const int t)
{
    const int tid  = threadIdx.x;
    const int row  = blockIdx.x;          // b*9 + h
    const int tile = blockIdx.y;          // 256 positions per tile
    const int b = row / 9, h = row - 9 * b;
    const float sm = m0prev ? m0prev[b] : 1.f;
    const float aU = aUp[0], aP = aPp[0];
    const float* xrow = xin + (size_t)row * (2 * t) * CB;
    const int p0 = tile * 256;
    const int j = p0 + tid;
    const bool valid = (j < t);

    const float* WU1t = Wt;
    const float* WU2t = Wt + 768;
    const float* WP1t = Wt + 1024;
    const float* WP2t = Wt + 1792;

    __shared__ float ldc[258 * LPITCH];   // c[p0-1 .. p0+256], idx = j-p0+1

    float cv[CB], ow1[CB];
#pragma unroll
    for (int i = 0; i < CB; ++i) { cv[i] = 0.f; ow1[i] = 0.f; }

    if (valid) {
        compute_c(xrow, j, t, sm, WU1t, WU2t, aU, cv, ow1);
        st16(&ldc[(tid + 1) * LPITCH], cv);
        st16(xout + ((size_t)row * t + j) * CB, cv);
    }
    if (tid < 2) {                         // halo (LDS only)
        int jx = (tid == 0) ? p0 - 1 : p0 + 256;
        if (jx >= 0 && jx < t) {
            float hv[CB], dump[CB];
            compute_c(xrow, jx, t, sm, WU1t, WU2t, aU, hv, dump);
            st16(&ldc[(jx - p0 + 1) * LPITCH], hv);
        }
    }

    rowsum_reduce(cv, rs, tile, b, h, 0, tid);   // leading sync -> ldc visible

    float dv[CB];
#pragma unroll
    for (int i = 0; i < CB; ++i) dv[i] = 0.f;

    if (valid) {
        float accz[CB];
#pragma unroll
        for (int i = 0; i < CB; ++i) accz[i] = 0.f;
#pragma unroll
        for (int k = 0; k < 3; ++k) {
            int um = refl(j - 1 + k, t);
            int li = um - p0 + 1;
            float cw[CB];
            ld16s(&ldc[li * LPITCH], cw);
#pragma unroll
            for (int c2 = 0; c2 < CB; ++c2) {
                float o = cw[c2];
                const float* wp = WP1t + (k * 16 + c2) * 16;
#pragma unroll
                for (int cc = 0; cc < CB; ++cc)
                    accz[cc] = fmaf(wp[cc], o, accz[cc]);
            }
        }
#pragma unroll
        for (int i = 0; i < CB; ++i) accz[i] = fprelu(accz[i], aP);
        float bacc[CB];
#pragma unroll
        for (int cc = 0; cc < CB; ++cc) bacc[cc] = 0.f;
#pragma unroll
        for (int c2 = 0; c2 < CB; ++c2) {
            float z = accz[c2];
            const float* wp = WP2t + c2 * 16;
#pragma unroll
            for (int cc = 0; cc < CB; ++cc)
                bacc[cc] = fmaf(wp[cc], z, bacc[cc]);
        }
#pragma unroll
        for (int cc = 0; cc < CB; ++cc)
            dv[cc] = sm * ow1[cc] - ftanh(bacc[cc]);
    }
    rowsum_reduce(dv, rs, tile, b, h, 1, tid);
}

// ---------------- Gate (levels 0..4): one block per bj = b*2+s ----------------
__global__ __launch_bounds__(192) void gate_kernel(
    const float* __restrict__ rs, const float* __restrict__ gn,
    const float* __restrict__ Wg1, const float* __restrict__ ag1p,
    const float* __restrict__ Wg2, const float* __restrict__ ag2p,
    float* __restrict__ out, float* __restrict__ m0buf,
    const int t, const int nt, const int li)
{
    const int bj  = blockIdx.x;
    const int tid = threadIdx.x;

    __shared__ float sums[144];
    __shared__ float sscale;

    if (tid < 144) {
        float s = 0.f;
        for (int tl = 0; tl < nt; ++tl)
            s += rs[(size_t)tl * RS_SLOT + (size_t)bj * 144 + tid];
        sums[tid] = s;
    }
    __syncthreads();

    if (tid == 0) {
        const float ag1 = ag1p[0], ag2 = ag2p[0];
        const float inv = 1.f / (9.f * (float)t);
        float pooled[CB];
#pragma unroll
        for (int cc = 0; cc < CB; ++cc) {
            float s = 0.f;
#pragma unroll
            for (int h = 0; h < HH; ++h) s += sums[cc * HH + h];
            pooled[cc] = s * inv;
        }
        float hm1[CB];
#pragma unroll
        for (int cc = 0; cc < CB; ++cc) {
            float s = 0.f;
#pragma unroll
            for (int c2 = 0; c2 < CB; ++c2) s = fmaf(Wg1[cc * CB + c2], pooled[c2], s);
            hm1[cc] = fprelu(s, ag1);
        }
        float h0 = 0.f, h1 = 0.f;
#pragma unroll
        for (int c2 = 0; c2 < CB; ++c2) {
            h0 = fmaf(Wg2[c2], hm1[c2], h0);
            h1 = fmaf(Wg2[CB + c2], hm1[c2], h1);
        }
        h0 = fprelu(h0, ag2); h1 = fprelu(h1, ag2);
        float mx = fmaxf(h0, h1);
        float e0 = __expf(h0 - mx), e1 = __expf(h1 - mx);
        float s0 = e0 / (e0 + e1), s1 = e1 / (e0 + e1);
        float a0 = s0 + gn[bj * 2 + 0], a1 = s1 + gn[bj * 2 + 1];
        float mx2 = fmaxf(a0, a1);
        float f0 = __expf(a0 - mx2), f1 = __expf(a1 - mx2);
        float m0 = f0 / (f0 + f1), m1 = f1 / (f0 + f1);
        sscale = m1 / (float)t;
        if ((bj & 1) == 0) m0buf[bj >> 1] = m0;
    }
    __syncthreads();

    if (tid < 144)
        out[(size_t)(bj * 144 + tid) * 9 + li] = sums[tid] * sscale;
}

// ---------------- Tail: levels 5..8 + gates, one block per batch b ----------------
// Channel-major LDS (odd pitch -> conflict-free), shfl-tree row sums (no atomics).
__global__ __launch_bounds__(256) void tail_kernel(
    const float* __restrict__ xin,      // level-5 input: (b*9+h, 64 pos, 16 ch)
    const float* __restrict__ m0in,
    const float* __restrict__ Wt,
    const float* __restrict__ aUa, const float* __restrict__ aPa,
    const float* __restrict__ gn,       // (L, 2B, 2)
    const float* __restrict__ Wg1a, const float* __restrict__ ag1a,
    const float* __restrict__ Wg2a, const float* __restrict__ ag2a,
    float* __restrict__ out)
{
    const int b   = blockIdx.x;
    const int tid = threadIdx.x;

    __shared__ float bufA[9 * 16 * 65];   // 9360 floats; pitch 65 (level-5 in)
    __shared__ float bufB[9 * 16 * 33];   // 4752 floats
    __shared__ float sums[288];           // [s][cc*9+h]
    __shared__ float sh_sm, sh_sc0, sh_sc1;

    // Stage level-5 input, transposing (pos,cc) -> channel-major pitch 65.
    for (int idx = tid; idx < 9216; idx += 256) {
        int h = idx >> 10, rem = idx & 1023, pos = rem >> 4, cc = rem & 15;
        bufA[(h * 16 + cc) * 65 + pos] = xin[(size_t)b * 9216 + idx];
    }
    if (tid == 0) sh_sm = m0in[b];
    __syncthreads();

    float* cur = bufA; int curp = 65;     // 2t positions, pitch curp
    float* cb  = bufB; int cbp  = 33;     // t positions, pitch cbp
    int t = 32;
    for (int l = 5; l <= 8; ++l) {
        const float* W    = Wt + 1296 + l * 2048;
        const float* WU1t = W;
        const float* WU2t = W + 768;
        const float* WP1t = W + 1024;
        const float* WP2t = W + 1792;
        const float aU = aUa[l], aP = aPa[l];
        const float sm = sh_sm;
        const int nItems = 9 * t;

        // ---- c-phase ----
        for (int base = 0; base < nItems; base += 256) {
            int item = base + tid;
            if (item < nItems) {
                int h = item / t, j = item - h * t;
                const float* xr = cur + (h * 16) * curp;
                float accz[CB];
#pragma unroll
                for (int i = 0; i < CB; ++i) accz[i] = 0.f;
#pragma unroll
                for (int k = 0; k < 3; ++k) {
                    int po = 2 * refl(j - 1 + k, t) + 1;
#pragma unroll
                    for (int c2 = 0; c2 < CB; ++c2) {
                        float o = xr[c2 * curp + po];
                        const float* wp = WU1t + (k * 16 + c2) * 16;
#pragma unroll
                        for (int cc = 0; cc < CB; ++cc)
                            accz[cc] = fmaf(wp[cc], o, accz[cc]);
                    }
                }
#pragma unroll
                for (int i = 0; i < CB; ++i) accz[i] = fprelu(accz[i], aU);
                float bacc[CB];
#pragma unroll
                for (int cc = 0; cc < CB; ++cc) bacc[cc] = 0.f;
#pragma unroll
                for (int c2 = 0; c2 < CB; ++c2) {
                    float z = accz[c2];
                    const float* wp = WU2t + c2 * 16;
#pragma unroll
                    for (int cc = 0; cc < CB; ++cc)
                        bacc[cc] = fmaf(wp[cc], z, bacc[cc]);
                }
                float cvv[CB];
#pragma unroll
                for (int cc = 0; cc < CB; ++cc) {
                    float ev = xr[cc * curp + 2 * j];
                    cvv[cc] = sm * ev + ftanh(sm * bacc[cc]);
                    cb[(h * 16 + cc) * cbp + j] = cvv[cc];
                }
                // shfl-tree reduction over the j-group (contiguous lanes)
#pragma unroll
                for (int cc = 0; cc < CB; ++cc) {
                    float s = cvv[cc];
                    for (int off = t >> 1; off >= 1; off >>= 1)
                        s += __shfl_xor(s, off, 64);
                    if (j == 0) sums[cc * HH + h] = s;
                }
            }
        }
        __syncthreads();

        // ---- d-phase ----
        for (int base = 0; base < nItems; base += 256) {
            int item = base + tid;
            if (item < nItems) {
                int h = item / t, j = item - h * t;
                const float* xr = cur + (h * 16) * curp;
                const float* cr = cb + (h * 16) * cbp;
                float accz[CB];
#pragma unroll
                for (int i = 0; i < CB; ++i) accz[i] = 0.f;
#pragma unroll
                for (int k = 0; k < 3; ++k) {
                    int um = refl(j - 1 + k, t);
#pragma unroll
                    for (int c2 = 0; c2 < CB; ++c2) {
                        float o = cr[c2 * cbp + um];
                        const float* wp = WP1t + (k * 16 + c2) * 16;
#pragma unroll
                        for (int cc = 0; cc < CB; ++cc)
                            accz[cc] = fmaf(wp[cc], o, accz[cc]);
                    }
                }
#pragma unroll
                for (int i = 0; i < CB; ++i) accz[i] = fprelu(accz[i], aP);
                float bacc[CB];
#pragma unroll
                for (int cc = 0; cc < CB; ++cc) bacc[cc] = 0.f;
#pragma unroll
                for (int c2 = 0; c2 < CB; ++c2) {
                    float z = accz[c2];
                    const float* wp = WP2t + c2 * 16;
#pragma unroll
                    for (int cc = 0; cc < CB; ++cc)
                        bacc[cc] = fmaf(wp[cc], z, bacc[cc]);
                }
                float dvv[CB];
#pragma unroll
                for (int cc = 0; cc < CB; ++cc) {
                    float ov = xr[cc * curp + 2 * j + 1];
                    dvv[cc] = sm * ov - ftanh(bacc[cc]);
                }
#pragma unroll
                for (int cc = 0; cc < CB; ++cc) {
                    float s = dvv[cc];
                    for (int off = t >> 1; off >= 1; off >>= 1)
                        s += __shfl_xor(s, off, 64);
                    if (j == 0) sums[144 + cc * HH + h] = s;
                }
            }
        }
        __syncthreads();

        // ---- gate (threads 0 and 1 handle s=0 / s=1) ----
        if (tid < 2) {
            const int s = tid;
            const float ag1 = ag1a[l], ag2 = ag2a[l];
            const float* Wg1 = Wg1a + l * 256;
            const float* Wg2 = Wg2a + l * 32;
            const float inv = 1.f / (9.f * (float)t);
            float pooled[CB];
#pragma unroll
            for (int cc = 0; cc < CB; ++cc) {
                float ss = 0.f;
#pragma unroll
                for (int h = 0; h < HH; ++h) ss += sums[s * 144 + cc * HH + h];
                pooled[cc] = ss * inv;
            }
            float hm1[CB];
#pragma unroll
            for (int cc = 0; cc < CB; ++cc) {
                float ss = 0.f;
#pragma unroll
                for (int c2 = 0; c2 < CB; ++c2) ss = fmaf(Wg1[cc * CB + c2], pooled[c2], ss);
                hm1[cc] = fprelu(ss, ag1);
            }
            float h0 = 0.f, h1 = 0.f;
#pragma unroll
            for (int c2 = 0; c2 < CB; ++c2) {
                h0 = fmaf(Wg2[c2], hm1[c2], h0);
                h1 = fmaf(Wg2[CB + c2], hm1[c2], h1);
            }
            h0 = fprelu(h0, ag2); h1 = fprelu(h1, ag2);
            float mx = fmaxf(h0, h1);
            float e0 = __expf(h0 - mx), e1 = __expf(h1 - mx);
            float s0 = e0 / (e0 + e1), s1 = e1 / (e0 + e1);
            const int bj = b * 2 + s;
            float a0 = s0 + gn[(size_t)l * 512 + bj * 2 + 0];
            float a1 = s1 + gn[(size_t)l * 512 + bj * 2 + 1];
            float mx2 = fmaxf(a0, a1);
            float f0 = __expf(a0 - mx2), f1 = __expf(a1 - mx2);
            float m0 = f0 / (f0 + f1), m1 = f1 / (f0 + f1);
            if (s == 0) { sh_sc0 = m1 / (float)t; sh_sm = m0; }
            else        { sh_sc1 = m1 / (float)t; }
        }
        __syncthreads();

        for (int idx = tid; idx < 288; idx += 256) {
            int s = idx / 144, rem = idx - s * 144;
            float sc = s ? sh_sc1 : sh_sc0;
            out[(size_t)(((b * 2 + s) * 144) + rem) * 9 + l] = sums[idx] * sc;
        }
        __syncthreads();

        // swap: c buffer becomes next level's input
        float* tmp = cur; cur = cb; cb = tmp;
        curp = cbp;
        t >>= 1;
        cbp = t + 1;
    }
}

extern "C" void kernel_launch(void* const* d_in, const int* in_sizes, int n_in,
                              void* d_out, int out_size, void* d_ws, size_t ws_size,
                              hipStream_t stream) {
    const float* x    = (const float*)d_in[0];
    const float* gn   = (const float*)d_in[1];
    const float* Wc1  = (const float*)d_in[2];
    const float* bc1  = (const float*)d_in[3];
    const float* bn1g = (const float*)d_in[4];
    const float* bn1b = (const float*)d_in[5];
    const float* ac1  = (const float*)d_in[6];
    const float* Wc2  = (const float*)d_in[7];
    const float* bc2  = (const float*)d_in[8];
    const float* bn2g = (const float*)d_in[9];
    const float* bn2b = (const float*)d_in[10];
    const float* ac2  = (const float*)d_in[11];
    const float* WP1  = (const float*)d_in[12];
    const float* aP   = (const float*)d_in[13];
    const float* WP2  = (const float*)d_in[14];
    const float* WU1  = (const float*)d_in[15];
    const float* aU   = (const float*)d_in[16];
    const float* WU2  = (const float*)d_in[17];
    const float* Wg1  = (const float*)d_in[18];
    const float* ag1  = (const float*)d_in[19];
    const float* Wg2  = (const float*)d_in[20];
    const float* ag2  = (const float*)d_in[21];
    float* out = (float*)d_out;

    char* ws = (char*)d_ws;
    const size_t sz0 = (size_t)128 * 9 * 2048 * 16 * 4;   // 150,994,944
    const size_t sz1 = sz0 / 2;
    float* buf0 = (float*)ws;
    float* buf1 = (float*)(ws + sz0);
    float* rs   = (float*)(ws + sz0 + sz1);
    float* m0b  = (float*)(ws + sz0 + sz1 + (size_t)4 * RS_SLOT * 4);
    float* wt   = (float*)(ws + sz0 + sz1 + (size_t)4 * RS_SLOT * 4 + 512);

    wtrans_kernel<<<1, 256, 0, stream>>>(Wc1, Wc2, WU1, WU2, WP1, WP2, wt);

    dim3 fgrid(9, 9, 128);
    front_kernel<<<fgrid, 256, 0, stream>>>(x, wt, bc1, bn1g, bn1b, ac1,
                                            bc2, bn2g, bn2b, ac2, buf0);

    float* cur = buf0;
    float* nxt = buf1;
    int t = 1024;
    for (int i = 0; i < 5; ++i) {
        const int nt = (t + 255) >> 8;
        const float* m0p = (i == 0) ? nullptr : m0b;
        const float* lw = wt + 1296 + i * 2048;
        dim3 lgrid(128 * 9, nt);
        cd_kernel<<<lgrid, 256, 0, stream>>>(cur, nxt, rs, m0p, lw, aU + i, aP + i, t);
        gate_kernel<<<256, 192, 0, stream>>>(
            rs, gn + i * 512, Wg1 + i * 256, ag1 + i, Wg2 + i * 32, ag2 + i,
            out, m0b, t, nt, i);
        float* tmp = cur; cur = nxt; nxt = tmp;
        t >>= 1;
    }
    // cur now holds level-5 input (t=64 rows).
    tail_kernel<<<128, 256, 0, stream>>>(cur, m0b, wt, aU, aP, gn,
                                         Wg1, ag1, Wg2, ag2, out);
}